// Round 1
// baseline (261.773 us; speedup 1.0000x reference)
//
#include <hip/hip_runtime.h>

// Patch-embedding rearrange: (B=256, C=3, H=224, W=224) fp32 -> (B, 196, 768)
// out[b][ph*14+pw][c*256+i*16+j] = in[b][c][ph*16+i][pw*16+j]
//
// R4: R3's half-slab structure, but phase-1 staging now uses
// __builtin_amdgcn_global_load_lds (dwordx4) instead of global->VGPR->ds_write.
//  - global_load_lds needs a LINEAR per-wave LDS destination (base + lane*16),
//    so the +1 padding (stride 57) is gone: LDS stride is 56, linear slot
//    s = (c*8+il)*56 + col, and each wave's 64 slots are contiguous.
//  - Bank conflicts are instead broken by an XOR swizzle carried on the
//    GLOBAL source address (m173 pattern): slot (c,il,col) holds input
//    column (col ^ il). col^il permutes only within aligned 8-float4
//    (128 B) groups, so global reads touch the same cache lines -> still
//    fully coalesced.
//  - Phase-2 read addr: (c*8+il)*56 + ((pw*4+j4) ^ il). Residue mod 8 is
//    (pw*4+j4)^il; over a wave (j4 0..3, il 0..7, 2 g-groups) each of the
//    8 bank-groups is hit exactly 8x -> conflict-free b128, same as R3.
//  - Writes unchanged: per (pw,c) a 512 B contiguous, 512 B-aligned run.

constexpr int B    = 256;
constexpr int C    = 3;
constexpr int H    = 224;
constexpr int P    = 16;
constexpr int PHN  = 14;
constexpr int PWN  = 14;
constexpr int W4   = 56;                 // float4 per image row
constexpr int HALF = 8;                  // rows per half-slab
constexpr int NV   = C * HALF * W4;      // 1344 float4 per half-slab
constexpr int TPB  = 448;               // 7 waves; 448 = 8*56 -> k == c slab
constexpr int ITERS = NV / TPB;          // 3, exact

typedef const __attribute__((address_space(1))) void g_void;
typedef __attribute__((address_space(3))) void l_void;

__global__ __launch_bounds__(TPB)
void patch_half_kernel(const float4* __restrict__ in, float4* __restrict__ out) {
    __shared__ float4 lds4[NV];          // 24*56*16 B = 21504 B, linear

    const int tid = threadIdx.x;
    int blk = blockIdx.x;                // 0 .. B*PHN*2-1
    const int h  = blk & 1;
    blk >>= 1;
    const int ph = blk % PHN;
    const int b  = blk / PHN;

    // ---- phase 1: DMA global -> LDS (no VGPR round trip) ----
    // slot (k*448 + tid) == (c*8+il)*56 + col with c=k, il=tid/56, col=tid%56
    const int il   = tid / W4;           // 0..7
    const int col  = tid - il * W4;      // 0..55
    const int colg = col ^ il;           // source-side swizzle (involution)
    const float4* src0 =
        in + ((size_t)(b * C) * H + ph * P + h * HALF + il) * W4 + colg;
    #pragma unroll
    for (int k = 0; k < ITERS; ++k) {
        __builtin_amdgcn_global_load_lds((g_void*)(src0 + (size_t)k * H * W4),
                                         (l_void*)&lds4[k * TPB + tid],
                                         16, 0, 0);
    }
    __syncthreads();                     // drains vmcnt -> LDS tile complete

    // ---- phase 2: batched LDS reads -> regs -> global stores ----
    // v enumerates output order: v = ((pw*C + c)*HALF + il)*4 + j4
    float4 s[ITERS];
    #pragma unroll
    for (int k = 0; k < ITERS; ++k) {
        int v   = tid + k * TPB;
        int j4  = v & 3;
        int il2 = (v >> 2) & (HALF - 1);
        int g   = v >> 5;                // pw*C + c
        int c   = g % C;
        int pw  = g / C;
        s[k] = lds4[(c * HALF + il2) * W4 + ((pw * 4 + j4) ^ il2)];
    }
    const int obase = (b * (PHN * PWN) + ph * PWN) * 192 + h * (HALF * 4);
    #pragma unroll
    for (int k = 0; k < ITERS; ++k) {
        int v   = tid + k * TPB;
        int j4  = v & 3;
        int il2 = (v >> 2) & (HALF - 1);
        int g   = v >> 5;
        int c   = g % C;
        int pw  = g / C;
        out[obase + pw * 192 + c * 64 + il2 * 4 + j4] = s[k];
    }
}

extern "C" void kernel_launch(void* const* d_in, const int* in_sizes, int n_in,
                              void* d_out, int out_size, void* d_ws, size_t ws_size,
                              hipStream_t stream) {
    const float4* in  = (const float4*)d_in[0];
    float4*       out = (float4*)d_out;
    patch_half_kernel<<<B * PHN * 2, TPB, 0, stream>>>(in, out);
}